// Round 3
// baseline (3415.068 us; speedup 1.0000x reference)
//
#include <hip/hip_runtime.h>
#include <hip/hip_bf16.h>
#include <stdint.h>

#define BATCH 2
#define LQ 2048
#define LK 2048
#define DIM 1024
#define HEADS 8
#define DH 64
#define INNER 512  // HEADS*DH

typedef __attribute__((ext_vector_type(8))) short short8;
typedef __attribute__((ext_vector_type(4))) float f32x4;

__device__ __forceinline__ float bf2f(unsigned short u) {
    union { unsigned int i; float f; } v;
    v.i = ((unsigned int)u) << 16;
    return v.f;
}
__device__ __forceinline__ unsigned short f2bf(float f) {
    __hip_bfloat16 h = __float2bfloat16(f);
    return *reinterpret_cast<unsigned short*>(&h);
}

// load 8 contiguous elements as bf16 into dst (16B-aligned source)
__device__ __forceinline__ void ld8(const unsigned short* p, unsigned short* d) {
    *(uint4*)d = *(const uint4*)p;
}
__device__ __forceinline__ void ld8(const float* p, unsigned short* d) {
    float4 f0 = *(const float4*)p;
    float4 f1 = *(const float4*)(p + 4);
    d[0] = f2bf(f0.x); d[1] = f2bf(f0.y); d[2] = f2bf(f0.z); d[3] = f2bf(f0.w);
    d[4] = f2bf(f1.x); d[5] = f2bf(f1.y); d[6] = f2bf(f1.z); d[7] = f2bf(f1.w);
}
__device__ __forceinline__ void stc(unsigned short* C, size_t i, float v) { C[i] = f2bf(v); }
__device__ __forceinline__ void stc(float* C, size_t i, float v) { C[i] = v; }

// ---------------------------------------------------------------------------
// C[M,N] = scale * (A[M,K] @ W[N,K]^T), fp32/bf16 in, fp32 accum, fp32/bf16
// out. 128x128 tile, BK=64, 256 thr = 4 waves (2x2 of 64x64). Plain padded
// LDS (stride 72 ushort = 144 B, rows 16B-aligned; 2-way bank aliasing on
// reads = free per m136). fp32 sources are converted to bf16 at stage time
// (no fp32-input MFMA on CDNA4).
// ---------------------------------------------------------------------------
#define LDT 72

template <typename TA, typename TW, typename TC>
__device__ __forceinline__ void gemm_body(
    const TA* __restrict__ A,
    const TW* __restrict__ W,
    TC* __restrict__ C,
    int K, int N, float scale,
    unsigned short* As, unsigned short* Bs)
{
    const int tid = threadIdx.x;
    const int m0 = blockIdx.x * 128;
    const int n0 = blockIdx.y * 128;
    const int w = tid >> 6, lane = tid & 63;
    const int q4 = lane >> 4, l16 = lane & 15;
    const int wm = (w >> 1) * 64, wn = (w & 1) * 64;

    f32x4 acc[4][4] = {};

    for (int kk = 0; kk < K; kk += 64) {
#pragma unroll
        for (int i = 0; i < 4; ++i) {
            int c = tid + i * 256;           // 1024 chunks of 8 elems
            int row = c >> 3, ch = c & 7;
            unsigned short ta[8], tb[8];
            ld8(A + (size_t)(m0 + row) * K + kk + ch * 8, ta);
            *(uint4*)(As + row * LDT + ch * 8) = *(uint4*)ta;
            ld8(W + (size_t)(n0 + row) * K + kk + ch * 8, tb);
            *(uint4*)(Bs + row * LDT + ch * 8) = *(uint4*)tb;
        }
        __syncthreads();

#pragma unroll
        for (int ks = 0; ks < 2; ++ks) {
            short8 a[4], b[4];
#pragma unroll
            for (int i = 0; i < 4; ++i)
                a[i] = *(const short8*)(As + (wm + i * 16 + l16) * LDT + (ks * 4 + q4) * 8);
#pragma unroll
            for (int j = 0; j < 4; ++j)
                b[j] = *(const short8*)(Bs + (wn + j * 16 + l16) * LDT + (ks * 4 + q4) * 8);
#pragma unroll
            for (int i = 0; i < 4; ++i)
#pragma unroll
                for (int j = 0; j < 4; ++j)
                    acc[i][j] = __builtin_amdgcn_mfma_f32_16x16x32_bf16(
                        a[i], b[j], acc[i][j], 0, 0, 0);
        }
        __syncthreads();
    }

    // C/D layout: col = lane&15, row = quad*4 + reg  [m89-verified]
#pragma unroll
    for (int i = 0; i < 4; ++i)
#pragma unroll
        for (int j = 0; j < 4; ++j)
#pragma unroll
            for (int r = 0; r < 4; ++r) {
                int row = m0 + wm + i * 16 + q4 * 4 + r;
                int col = n0 + wn + j * 16 + l16;
                stc(C, (size_t)row * N + col, acc[i][j][r] * scale);
            }
}

// z=0: q = 0.125 * x @ Wq^T ; z=1: k = y @ Wk^T ; z=2: v = y @ Wv^T
__global__ __launch_bounds__(256) void proj_qkv(
    const float* __restrict__ x,
    const float* __restrict__ y,
    const float* __restrict__ Wq,
    const float* __restrict__ Wk,
    const float* __restrict__ Wv,
    unsigned short* __restrict__ qb,
    unsigned short* __restrict__ kb,
    unsigned short* __restrict__ vb)
{
    __shared__ __align__(16) unsigned short As[128 * LDT];
    __shared__ __align__(16) unsigned short Bs[128 * LDT];
    const int z = blockIdx.z;
    const float* A = (z == 0) ? x : y;
    const float* W = (z == 0) ? Wq : (z == 1) ? Wk : Wv;
    unsigned short* C = (z == 0) ? qb : (z == 1) ? kb : vb;
    float scale = (z == 0) ? 0.125f : 1.0f;  // DH^-0.5 folded into q
    gemm_body(A, W, C, DIM, INNER, scale, As, Bs);
}

__global__ __launch_bounds__(256) void gemm_out(
    const unsigned short* __restrict__ A,
    const float* __restrict__ W,
    float* __restrict__ C)
{
    __shared__ __align__(16) unsigned short As[128 * LDT];
    __shared__ __align__(16) unsigned short Bs[128 * LDT];
    gemm_body(A, W, C, INNER, DIM, 1.0f, As, Bs);
}

// ---------------------------------------------------------------------------
// Correctness-first attention: 1 wave per 64 q-rows of one (b,h); thread =
// one q row. K/V rows loaded coalesced (lane = dim) and broadcast via __shfl.
// Online softmax in fp32. Mask read directly as fp32.
// ---------------------------------------------------------------------------
__global__ __launch_bounds__(64) void attn_simple(
    const unsigned short* __restrict__ Q,
    const unsigned short* __restrict__ Kb,
    const unsigned short* __restrict__ Vb,
    const float* __restrict__ Mask,
    unsigned short* __restrict__ O)
{
    const int lane = threadIdx.x;            // 0..63
    const int q0 = blockIdx.x * 64;
    const int h = blockIdx.y, b = blockIdx.z;
    const int q = q0 + lane;

    const unsigned short* qp = Q + ((size_t)(b * LQ + q)) * INNER + h * DH;
    float qv[64];
#pragma unroll
    for (int d = 0; d < 64; ++d) qv[d] = bf2f(qp[d]);

    float o[64];
#pragma unroll
    for (int d = 0; d < 64; ++d) o[d] = 0.f;
    float m = -1e30f, l = 0.f;

    const unsigned short* kp = Kb + ((size_t)b * LK) * INNER + h * DH;
    const unsigned short* vp = Vb + ((size_t)b * LK) * INNER + h * DH;
    const float* mp = Mask + (size_t)b * LQ * LK + (size_t)q * LK;

    for (int key = 0; key < LK; ++key) {
        float kd = bf2f(kp[(size_t)key * INNER + lane]);  // lane = dim
        float d0 = 0.f, d1 = 0.f, d2 = 0.f, d3 = 0.f;
#pragma unroll
        for (int j = 0; j < 64; j += 4) {
            d0 = fmaf(qv[j + 0], __shfl(kd, j + 0), d0);
            d1 = fmaf(qv[j + 1], __shfl(kd, j + 1), d1);
            d2 = fmaf(qv[j + 2], __shfl(kd, j + 2), d2);
            d3 = fmaf(qv[j + 3], __shfl(kd, j + 3), d3);
        }
        float sv = (d0 + d1) + (d2 + d3) - 1e9f * mp[key];

        if (sv > m) {                        // new running max: rescale
            float al = __expf(m - sv);
            l *= al;
#pragma unroll
            for (int d = 0; d < 64; ++d) o[d] *= al;
            m = sv;
        }
        float e = __expf(sv - m);            // <= 1
        l += e;

        float vd = bf2f(vp[(size_t)key * INNER + lane]);
#pragma unroll
        for (int j = 0; j < 64; ++j)
            o[j] = fmaf(e, __shfl(vd, j), o[j]);
    }

    unsigned short* op = O + ((size_t)(b * LQ + q)) * INNER + h * DH;
    float inv = 1.0f / l;                    // l >= 1 always
#pragma unroll
    for (int d = 0; d < 64; ++d) op[d] = f2bf(o[d] * inv);
}

extern "C" void kernel_launch(void* const* d_in, const int* in_sizes, int n_in,
                              void* d_out, int out_size, void* d_ws, size_t ws_size,
                              hipStream_t stream) {
    const float* x    = (const float*)d_in[0];
    const float* y    = (const float*)d_in[1];
    const float* mask = (const float*)d_in[2];
    const float* Wq   = (const float*)d_in[3];
    const float* Wk   = (const float*)d_in[4];
    const float* Wv   = (const float*)d_in[5];
    const float* Wo   = (const float*)d_in[6];
    float* out = (float*)d_out;

    unsigned short* qb = (unsigned short*)d_ws;
    unsigned short* kb = qb + (size_t)BATCH * LQ * INNER;
    unsigned short* vb = kb + (size_t)BATCH * LK * INNER;
    unsigned short* ao = vb + (size_t)BATCH * LK * INNER;
    // ws usage: 4 * 2*2048*512 * 2B = 16 MB

    dim3 blk(256);
    proj_qkv<<<dim3(4096 / 128, INNER / 128, 3), blk, 0, stream>>>(
        x, y, Wq, Wk, Wv, qb, kb, vb);
    attn_simple<<<dim3(LQ / 64, HEADS, BATCH), dim3(64), 0, stream>>>(
        qb, kb, vb, mask, ao);
    gemm_out<<<dim3(4096 / 128, DIM / 128), blk, 0, stream>>>(ao, Wo, out);
}

// Round 4
// 232.858 us; speedup vs baseline: 14.6659x; 14.6659x over previous
//
#include <hip/hip_runtime.h>
#include <hip/hip_bf16.h>
#include <stdint.h>

#define BATCH 2
#define LQ 2048
#define LK 2048
#define DIM 1024
#define HEADS 8
#define DH 64
#define INNER 512  // HEADS*DH

typedef __attribute__((ext_vector_type(8))) short short8;
typedef __attribute__((ext_vector_type(4))) float f32x4;

__device__ __forceinline__ float bf2f(unsigned short u) {
    union { unsigned int i; float f; } v;
    v.i = ((unsigned int)u) << 16;
    return v.f;
}
__device__ __forceinline__ unsigned short f2bf(float f) {
    __hip_bfloat16 h = __float2bfloat16(f);
    return *reinterpret_cast<unsigned short*>(&h);
}

__device__ __forceinline__ void ld8(const unsigned short* p, unsigned short* d) {
    *(uint4*)d = *(const uint4*)p;
}
__device__ __forceinline__ void ld8(const float* p, unsigned short* d) {
    float4 f0 = *(const float4*)p;
    float4 f1 = *(const float4*)(p + 4);
    d[0] = f2bf(f0.x); d[1] = f2bf(f0.y); d[2] = f2bf(f0.z); d[3] = f2bf(f0.w);
    d[4] = f2bf(f1.x); d[5] = f2bf(f1.y); d[6] = f2bf(f1.z); d[7] = f2bf(f1.w);
}
__device__ __forceinline__ void stc(unsigned short* C, size_t i, float v) { C[i] = f2bf(v); }
__device__ __forceinline__ void stc(float* C, size_t i, float v) { C[i] = v; }

// ---------------------------------------------------------------------------
// C[M,N] = scale * (A[M,K] @ W[N,K]^T)  [certified in R3]
// ---------------------------------------------------------------------------
#define LDT 72

template <typename TA, typename TW, typename TC>
__device__ __forceinline__ void gemm_body(
    const TA* __restrict__ A,
    const TW* __restrict__ W,
    TC* __restrict__ C,
    int K, int N, float scale,
    unsigned short* As, unsigned short* Bs)
{
    const int tid = threadIdx.x;
    const int m0 = blockIdx.x * 128;
    const int n0 = blockIdx.y * 128;
    const int w = tid >> 6, lane = tid & 63;
    const int q4 = lane >> 4, l16 = lane & 15;
    const int wm = (w >> 1) * 64, wn = (w & 1) * 64;

    f32x4 acc[4][4] = {};

    for (int kk = 0; kk < K; kk += 64) {
#pragma unroll
        for (int i = 0; i < 4; ++i) {
            int c = tid + i * 256;
            int row = c >> 3, ch = c & 7;
            unsigned short ta[8], tb[8];
            ld8(A + (size_t)(m0 + row) * K + kk + ch * 8, ta);
            *(uint4*)(As + row * LDT + ch * 8) = *(uint4*)ta;
            ld8(W + (size_t)(n0 + row) * K + kk + ch * 8, tb);
            *(uint4*)(Bs + row * LDT + ch * 8) = *(uint4*)tb;
        }
        __syncthreads();

#pragma unroll
        for (int ks = 0; ks < 2; ++ks) {
            short8 a[4], b[4];
#pragma unroll
            for (int i = 0; i < 4; ++i)
                a[i] = *(const short8*)(As + (wm + i * 16 + l16) * LDT + (ks * 4 + q4) * 8);
#pragma unroll
            for (int j = 0; j < 4; ++j)
                b[j] = *(const short8*)(Bs + (wn + j * 16 + l16) * LDT + (ks * 4 + q4) * 8);
#pragma unroll
            for (int i = 0; i < 4; ++i)
#pragma unroll
                for (int j = 0; j < 4; ++j)
                    acc[i][j] = __builtin_amdgcn_mfma_f32_16x16x32_bf16(
                        a[i], b[j], acc[i][j], 0, 0, 0);
        }
        __syncthreads();
    }

#pragma unroll
    for (int i = 0; i < 4; ++i)
#pragma unroll
        for (int j = 0; j < 4; ++j)
#pragma unroll
            for (int r = 0; r < 4; ++r) {
                int row = m0 + wm + i * 16 + q4 * 4 + r;
                int col = n0 + wn + j * 16 + l16;
                stc(C, (size_t)row * N + col, acc[i][j][r] * scale);
            }
}

__global__ __launch_bounds__(256) void proj_qkv(
    const float* __restrict__ x, const float* __restrict__ y,
    const float* __restrict__ Wq, const float* __restrict__ Wk,
    const float* __restrict__ Wv,
    unsigned short* __restrict__ qb, unsigned short* __restrict__ kb,
    unsigned short* __restrict__ vb)
{
    __shared__ __align__(16) unsigned short As[128 * LDT];
    __shared__ __align__(16) unsigned short Bs[128 * LDT];
    const int z = blockIdx.z;
    const float* A = (z == 0) ? x : y;
    const float* W = (z == 0) ? Wq : (z == 1) ? Wk : Wv;
    unsigned short* C = (z == 0) ? qb : (z == 1) ? kb : vb;
    float scale = (z == 0) ? 0.125f : 1.0f;  // DH^-0.5 folded into q
    gemm_body(A, W, C, DIM, INNER, scale, As, Bs);
}

__global__ __launch_bounds__(256) void gemm_out(
    const unsigned short* __restrict__ A,
    const float* __restrict__ W,
    float* __restrict__ C)
{
    __shared__ __align__(16) unsigned short As[128 * LDT];
    __shared__ __align__(16) unsigned short Bs[128 * LDT];
    gemm_body(A, W, C, INNER, DIM, 1.0f, As, Bs);
}

// ---------------------------------------------------------------------------
// vt[b][h][d][key] = v[b][key][h*DH+d]  — one 64x64 tile per block via LDS.
// ---------------------------------------------------------------------------
__global__ __launch_bounds__(256) void transpose_v(
    const unsigned short* __restrict__ V,
    unsigned short* __restrict__ Vt)
{
    __shared__ __align__(16) unsigned short T[64 * LDT];
    const int tid = threadIdx.x;
    const int kt0 = blockIdx.x * 64;
    const int h = blockIdx.y, b = blockIdx.z;

#pragma unroll
    for (int i = 0; i < 2; ++i) {
        int c = tid + i * 256;               // 512 chunks of 8
        int key = c >> 3, ch = c & 7;
        *(uint4*)(T + key * LDT + ch * 8) =
            *(const uint4*)(V + (size_t)(b * LK + kt0 + key) * INNER + h * DH + ch * 8);
    }
    __syncthreads();
#pragma unroll
    for (int i = 0; i < 2; ++i) {
        int c = tid + i * 256;
        int d = c >> 3, ch = c & 7;          // output row = d, keys ch*8..+7
        unsigned short tmp[8];
#pragma unroll
        for (int j = 0; j < 8; ++j) tmp[j] = T[(ch * 8 + j) * LDT + d];
        *(uint4*)(Vt + ((size_t)((b * HEADS + h) * DH + d)) * LK + kt0 + ch * 8) =
            *(uint4*)tmp;
    }
}

// ---------------------------------------------------------------------------
// Flash attention: block = 4 waves = 64 q rows of one (b,h); wave owns 16 q.
// K staged [key][d], V^T staged [d][key] (from pre-transposed vt), mask read
// directly from global fp32. QK^T and PV via MFMA 16x16x32; P round-trips
// through per-wave LDS (C-layout -> A-layout). Online softmax in fp32.
// ---------------------------------------------------------------------------
__global__ __launch_bounds__(256) void attn_mfma(
    const unsigned short* __restrict__ Q,
    const unsigned short* __restrict__ Kb,
    const unsigned short* __restrict__ Vt,
    const float* __restrict__ Mask,
    unsigned short* __restrict__ O)
{
    __shared__ __align__(16) unsigned short Ks[64 * LDT];
    __shared__ __align__(16) unsigned short Vs[64 * LDT];
    __shared__ __align__(16) unsigned short Ps[4][16 * LDT];

    const int tid = threadIdx.x;
    const int q0 = blockIdx.x * 64;
    const int h = blockIdx.y, b = blockIdx.z;
    const int w = tid >> 6, lane = tid & 63;
    const int q4 = lane >> 4, l16 = lane & 15;

    // Q fragment: A[m=l16][k=q4*8+j], two 32-wide k-chunks
    short8 qf[2];
    {
        const unsigned short* qp =
            Q + (size_t)(b * LQ + q0 + w * 16 + l16) * INNER + h * DH + q4 * 8;
        qf[0] = *(const short8*)(qp);
        qf[1] = *(const short8*)(qp + 32);
    }

    f32x4 o[4] = {};
    float mrow[4], lrow[4];
#pragma unroll
    for (int r = 0; r < 4; ++r) { mrow[r] = -3e38f; lrow[r] = 0.f; }

    const float* mbase = Mask + (size_t)b * LQ * LK;
    const unsigned short* kbase = Kb + (size_t)(b * LK) * INNER + h * DH;
    const unsigned short* vbase = Vt + (size_t)((b * HEADS + h) * DH) * LK;

    for (int kt = 0; kt < LK; kt += 64) {
        // ---- stage K [key][d] and V^T [d][key], both plain uint4 ----
#pragma unroll
        for (int i = 0; i < 2; ++i) {
            int c = tid + i * 256;
            int row = c >> 3, ch = c & 7;
            *(uint4*)(Ks + row * LDT + ch * 8) =
                *(const uint4*)(kbase + (size_t)(kt + row) * INNER + ch * 8);
            *(uint4*)(Vs + row * LDT + ch * 8) =
                *(const uint4*)(vbase + (size_t)row * LK + kt + ch * 8);
        }
        __syncthreads();

        // ---- S = Q K^T ----
        f32x4 s[4];
#pragma unroll
        for (int j = 0; j < 4; ++j) {
            s[j] = f32x4{0.f, 0.f, 0.f, 0.f};
#pragma unroll
            for (int ks = 0; ks < 2; ++ks) {
                short8 kf = *(const short8*)(Ks + (j * 16 + l16) * LDT + ks * 32 + q4 * 8);
                s[j] = __builtin_amdgcn_mfma_f32_16x16x32_bf16(qf[ks], kf, s[j], 0, 0, 0);
            }
        }

        // ---- mask + online softmax; row = w*16 + q4*4 + r, col = j*16+l16 ----
        float p[4][4];
#pragma unroll
        for (int r = 0; r < 4; ++r) {
            int qg = q0 + w * 16 + q4 * 4 + r;
            const float* mp = mbase + (size_t)qg * LK + kt;
            float rm = -3e38f;
#pragma unroll
            for (int j = 0; j < 4; ++j) {
                float sv = s[j][r] - 1e9f * mp[j * 16 + l16];
                p[j][r] = sv;
                rm = fmaxf(rm, sv);
            }
#pragma unroll
            for (int off = 1; off < 16; off <<= 1)
                rm = fmaxf(rm, __shfl_xor(rm, off));
            float mnew = fmaxf(mrow[r], rm);
            float alpha = __expf(mrow[r] - mnew);
            float rs = 0.f;
#pragma unroll
            for (int j = 0; j < 4; ++j) {
                float e = __expf(p[j][r] - mnew);
                p[j][r] = e;
                rs += e;
            }
#pragma unroll
            for (int off = 1; off < 16; off <<= 1)
                rs += __shfl_xor(rs, off);
            lrow[r] = lrow[r] * alpha + rs;
            mrow[r] = mnew;
#pragma unroll
            for (int d = 0; d < 4; ++d) o[d][r] *= alpha;
        }

        // ---- P (C-layout) -> per-wave LDS -> A-layout fragments ----
#pragma unroll
        for (int j = 0; j < 4; ++j)
#pragma unroll
            for (int r = 0; r < 4; ++r)
                Ps[w][(q4 * 4 + r) * LDT + j * 16 + l16] = f2bf(p[j][r]);
        __syncthreads();  // orders P writes vs reads (and is harmless)

        // ---- O += P V ----
#pragma unroll
        for (int ks = 0; ks < 2; ++ks) {
            short8 pf = *(const short8*)(&Ps[w][l16 * LDT + ks * 32 + q4 * 8]);
#pragma unroll
            for (int dd = 0; dd < 4; ++dd) {
                short8 vf = *(const short8*)(Vs + (dd * 16 + l16) * LDT + ks * 32 + q4 * 8);
                o[dd] = __builtin_amdgcn_mfma_f32_16x16x32_bf16(pf, vf, o[dd], 0, 0, 0);
            }
        }
        __syncthreads();  // protect Ks/Vs/Ps before next staging
    }

    // ---- normalize and store (C-layout) ----
#pragma unroll
    for (int dd = 0; dd < 4; ++dd)
#pragma unroll
        for (int r = 0; r < 4; ++r) {
            int qrow = b * LQ + q0 + w * 16 + q4 * 4 + r;
            int col = h * DH + dd * 16 + l16;
            O[(size_t)qrow * INNER + col] = f2bf(o[dd][r] / lrow[r]);
        }
}

extern "C" void kernel_launch(void* const* d_in, const int* in_sizes, int n_in,
                              void* d_out, int out_size, void* d_ws, size_t ws_size,
                              hipStream_t stream) {
    const float* x    = (const float*)d_in[0];
    const float* y    = (const float*)d_in[1];
    const float* mask = (const float*)d_in[2];
    const float* Wq   = (const float*)d_in[3];
    const float* Wk   = (const float*)d_in[4];
    const float* Wv   = (const float*)d_in[5];
    const float* Wo   = (const float*)d_in[6];
    float* out = (float*)d_out;

    const size_t SLICE = (size_t)BATCH * LQ * INNER;  // 2M elems = 4MB bf16
    unsigned short* qb = (unsigned short*)d_ws;
    unsigned short* kb = qb + SLICE;
    unsigned short* vb = kb + SLICE;
    unsigned short* vt = vb + SLICE;
    unsigned short* ao = vb;   // vb is dead after transpose_v; reuse for ao
    // ws usage: 4 slices * 4MB = 16MB

    dim3 blk(256);
    proj_qkv<<<dim3(4096 / 128, INNER / 128, 3), blk, 0, stream>>>(
        x, y, Wq, Wk, Wv, qb, kb, vb);
    transpose_v<<<dim3(LK / 64, HEADS, BATCH), blk, 0, stream>>>(vb, vt);
    attn_mfma<<<dim3(LQ / 64, HEADS, BATCH), blk, 0, stream>>>(
        qb, kb, vt, mask, ao);
    gemm_out<<<dim3(4096 / 128, DIM / 128), blk, 0, stream>>>(ao, Wo, out);
}